// Round 6
// baseline (85.227 us; speedup 1.0000x reference)
//
#include <hip/hip_runtime.h>
#include <hip/hip_bf16.h>
#include <math.h>

// ---------------------------------------------------------------------------
// RnCLoss, fully fused single kernel (one graph node + tiny memset node).
//   loss = -1/(n(n-1)) * sum_{i,k!=i} [ logit(i,k) - log denom(i,k) ]
//   logit(i,j) = 0.5*sqrt(max(2 - 2*G_ij*rsqrt(G_ii*G_jj), 0)), G = F F^T
//   denom(i,k) = sum_{j!=i, |l_i-l_j| >= |l_i-l_k|} exp(logit(i,j))
//
// Structure (512 blocks x 256 thr, __launch_bounds__(256,2) -> all blocks
// co-resident at 2/CU, so grid barriers are deadlock-free):
//   A: block b: bf16 fragment-swizzle tile b of F (wave 0) + norm row b (all)
//   -- flag barrier 1 --
//   B: waves 0,1: MFMA fragments 2b, 2b+1 of G (coalesced loads from Fb)
//   -- flag barrier 2 --
//   C: block b: row-b masked-denominator loss -> row_sums[b] + flagC
//      block 0: poll flagC, fixed-order final reduction -> out
//
// Barrier protocol (the R4 fix): arrival = plain RELEASE store to a
// per-block cacheline-distinct flag (no RMW serialization; release emits the
// L2 writeback that publishes the phase's plain stores). Wait = all threads
// vector-poll all flags (coalesced agent loads) + __syncthreads_and + long
// s_sleep backoff; ONE acquire fence on exit (single L2 invalidate) makes
// subsequent plain loads coherent. Flags zeroed per call by a memset node.
// All reductions fixed-order -> deterministic.
// ---------------------------------------------------------------------------

typedef __attribute__((ext_vector_type(8))) short short8;
typedef __attribute__((ext_vector_type(4))) float f32x4;

static __device__ __forceinline__ unsigned short bf16_bits(float f) {
    __hip_bfloat16 h = __float2bfloat16(f);  // RNE
    return *reinterpret_cast<unsigned short*>(&h);
}

// Contention-free grid barrier. flags[gridDim.x] zeroed before launch.
static __device__ __forceinline__ void grid_barrier(unsigned* flags) {
    const int t = threadIdx.x;
    const int nblk = gridDim.x;
    __syncthreads();  // all waves' plain stores issued & drained (vmcnt0)
    if (t == 0)
        __hip_atomic_store(&flags[blockIdx.x], 1u, __ATOMIC_RELEASE,
                           __HIP_MEMORY_SCOPE_AGENT);  // publishes L2 -> CP
    for (int round = 0;; ++round) {
        unsigned all = 1u;
        for (int x = t; x < nblk; x += 256)
            all &= __hip_atomic_load(&flags[x], __ATOMIC_RELAXED,
                                     __HIP_MEMORY_SCOPE_AGENT);
        if (__syncthreads_and((int)all)) break;
        if ((round & 7) == 7)  // progress guarantee if relaxed loads cache
            __builtin_amdgcn_fence(__ATOMIC_ACQUIRE, "agent");
        __builtin_amdgcn_s_sleep(4);
    }
    __builtin_amdgcn_fence(__ATOMIC_ACQUIRE, "agent");  // inv L2 once
}

// Fb layout: tile b=(r*16+s), r=rowblock, s=ksub. ushort idx: b*512+lane*8+e
// element: F[r*16+(lane&15)][s*32+(lane>>4)*8+e]. k-permutation is
// dot-invariant; G symmetric -> frag transpose harmless (validated R2-R5).
__global__ __launch_bounds__(256, 2) void k_fused(
        const float* __restrict__ F, const float* __restrict__ labels,
        unsigned short* __restrict__ Fb, float* __restrict__ G,
        float* __restrict__ norms, float* __restrict__ row_sums,
        unsigned* __restrict__ flagsA, unsigned* __restrict__ flagsB,
        unsigned* __restrict__ flagsC, float* __restrict__ out,
        int n, int d) {
    const int b    = blockIdx.x;
    const int t    = threadIdx.x;
    const int lane = t & 63;
    const int w    = t >> 6;

    __shared__ float2 lde[512];
    __shared__ float  lab_s[512];
    __shared__ float  nrm_s[512];
    __shared__ float  red[4];

    // ---- phase A: swizzle tile b (wave 0) + norm of row b (all waves) ----
    if (w == 0) {
        const int r = b >> 4, s = b & 15;
        const float* src =
            &F[(size_t)(r * 16 + (lane & 15)) * d + s * 32 + ((lane >> 4) << 3)];
        float4 a0 = *(const float4*)src;
        float4 a1 = *(const float4*)(src + 4);
        short8 v;
        v[0] = (short)bf16_bits(a0.x); v[1] = (short)bf16_bits(a0.y);
        v[2] = (short)bf16_bits(a0.z); v[3] = (short)bf16_bits(a0.w);
        v[4] = (short)bf16_bits(a1.x); v[5] = (short)bf16_bits(a1.y);
        v[6] = (short)bf16_bits(a1.z); v[7] = (short)bf16_bits(a1.w);
        *(short8*)&Fb[(size_t)b * 512 + lane * 8] = v;  // coalesced 1KB store
    }
    {
        float2 v = *(const float2*)&F[(size_t)b * d + t * 2];
        float s = v.x * v.x + v.y * v.y;
        #pragma unroll
        for (int off = 32; off > 0; off >>= 1) s += __shfl_down(s, off);
        if (lane == 0) red[w] = s;
        __syncthreads();
        if (t == 0) norms[b] = red[0] + red[1] + red[2] + red[3];
    }

    grid_barrier(flagsA);

    // ---- phase B: waves 0,1 compute MFMA fragments 2b, 2b+1 ----
    if (w < 2) {
        const int f  = b * 2 + w;        // fragment id in 32x32 grid
        const int fi = f >> 5;
        const int fj = f & 31;
        const short8* A = (const short8*)&Fb[(size_t)fi * 16 * 512 + lane * 8];
        const short8* B = (const short8*)&Fb[(size_t)fj * 16 * 512 + lane * 8];

        f32x4 acc = {};
        #pragma unroll
        for (int s = 0; s < 16; ++s) {
            short8 av = A[s * 64];       // tile (fi,s): +512 ushorts
            short8 bv = B[s * 64];
            acc = __builtin_amdgcn_mfma_f32_16x16x32_bf16(av, bv, acc, 0, 0, 0);
        }
        // C/D: col = lane&15, row = (lane>>4)*4 + r  (G symmetric)
        const int orow = fi * 16 + ((lane >> 4) << 2);
        const int ocol = fj * 16 + (lane & 15);
        #pragma unroll
        for (int r = 0; r < 4; ++r)
            G[(size_t)(orow + r) * n + ocol] = acc[r];
    }

    grid_barrier(flagsB);

    // ---- phase C: loss for row i = b ----
    const int i = b;
    for (int j = t; j < n; j += 256) {
        lab_s[j] = labels[j];
        nrm_s[j] = norms[j];
    }
    __syncthreads();

    const float li = lab_s[i];
    const float di = nrm_s[i];
    const float* Grow = G + (size_t)i * n;

    float lgt[2], ldk[2];
    #pragma unroll
    for (int q = 0; q < 2; ++q) {
        int j = t + q * 256;
        float g  = Grow[j] * rsqrtf(di * nrm_s[j]);
        float sq = fmaxf(2.f - 2.f * g, 0.f);
        float lg = 0.5f * sqrtf(sq);
        float e  = (j == i) ? 0.f : expf(lg);
        float ld = fabsf(li - lab_s[j]);
        lde[j] = make_float2(ld, e);
        lgt[q] = lg;
        ldk[q] = ld;
    }
    __syncthreads();

    float s0 = 0.f, s1 = 0.f;
    #pragma unroll 8
    for (int j = 0; j < n; ++j) {
        float2 p = lde[j];  // wave-uniform address -> LDS broadcast
        s0 += (p.x >= ldk[0]) ? p.y : 0.f;
        s1 += (p.x >= ldk[1]) ? p.y : 0.f;
    }

    float acc = 0.f;
    if (t != i)       acc += lgt[0] - logf(s0);
    if (t + 256 != i) acc += lgt[1] - logf(s1);

    #pragma unroll
    for (int off = 32; off > 0; off >>= 1) acc += __shfl_down(acc, off);
    if (lane == 0) red[w] = acc;
    __syncthreads();
    if (t == 0) {
        row_sums[i] = red[0] + red[1] + red[2] + red[3];  // plain store
        __hip_atomic_store(&flagsC[i], 1u, __ATOMIC_RELEASE,
                           __HIP_MEMORY_SCOPE_AGENT);     // publish
    }

    // ---- finalize: block 0 polls row flags, fixed-order reduce ----
    if (b == 0) {
        for (int round = 0;; ++round) {
            unsigned all = 1u;
            for (int x = t; x < n; x += 256)
                all &= __hip_atomic_load(&flagsC[x], __ATOMIC_RELAXED,
                                         __HIP_MEMORY_SCOPE_AGENT);
            if (__syncthreads_and((int)all)) break;
            if ((round & 7) == 7)
                __builtin_amdgcn_fence(__ATOMIC_ACQUIRE, "agent");
            __builtin_amdgcn_s_sleep(4);
        }
        __builtin_amdgcn_fence(__ATOMIC_ACQUIRE, "agent");

        float s = 0.f;
        for (int r = t; r < n; r += 256) s += row_sums[r];
        #pragma unroll
        for (int off = 32; off > 0; off >>= 1) s += __shfl_down(s, off);
        if (lane == 0) red[w] = s;
        __syncthreads();
        if (t == 0) {
            float tot = red[0] + red[1] + red[2] + red[3];
            out[0] = -tot / ((float)n * ((float)n - 1.0f));
        }
    }
}

extern "C" void kernel_launch(void* const* d_in, const int* in_sizes, int n_in,
                              void* d_out, int out_size, void* d_ws, size_t ws_size,
                              hipStream_t stream) {
    const float* F      = (const float*)d_in[0];
    const float* labels = (const float*)d_in[1];
    int n = in_sizes[1];            // 512
    int d = in_sizes[0] / n;        // 512
    float* out = (float*)d_out;

    char* ws = (char*)d_ws;
    unsigned* flagsA   = (unsigned*)(ws + 0);        // 512 u32
    unsigned* flagsB   = (unsigned*)(ws + 2048);     // 512 u32
    unsigned* flagsC   = (unsigned*)(ws + 4096);     // 512 u32
    float* norms       = (float*)(ws + 8192);        // n floats
    float* row_sums    = (float*)(ws + 16384);       // n floats
    unsigned short* Fb = (unsigned short*)(ws + 32768);          // n*d bf16
    float* G           = (float*)(ws + 32768 + (size_t)n * d * 2);  // n*n fp32

    // reset barrier flags every call (ws is poisoned 0xAA pre-timing)
    hipMemsetAsync(ws, 0, 6144, stream);
    k_fused<<<n, 256, 0, stream>>>(F, labels, Fb, G, norms, row_sums,
                                   flagsA, flagsB, flagsC, out, n, d);
}

// Round 7
// 44.778 us; speedup vs baseline: 1.9033x; 1.9033x over previous
//
#include <hip/hip_runtime.h>
#include <hip/hip_bf16.h>
#include <math.h>

// ---------------------------------------------------------------------------
// RnCLoss: loss = -1/(n(n-1)) * sum_{i,k!=i} [ logit(i,k) - log denom(i,k) ]
//   logit(i,j) = 0.5*sqrt(max(2 - 2*G_ij*rsqrt(G_ii*G_jj), 0)), G = F F^T
//   denom(i,k) = sum_{j!=i, |l_i-l_j| >= |l_i-l_k|} exp(logit(i,j))
//
// Kernel 1: bf16-MFMA GEMM G = F F^T + diag + counter reset (R3, proven).
// Kernel 2: per-row loss via SORT + SUFFIX-SUM (O(n log n) per row instead
//           of O(n^2)): bitonic-sort (ld,e) pairs by ld, suffix-sum e, then
//           denom(k) = suffix[lower_bound(ld_k)]. Mask semantics (>=, ties)
//           preserved exactly; only fp summation order differs (rounding).
// ---------------------------------------------------------------------------

typedef __attribute__((ext_vector_type(8))) short          short8;
typedef __attribute__((ext_vector_type(8))) unsigned short ushort8;
typedef __attribute__((ext_vector_type(4))) float          f32x4;

static __device__ __forceinline__ unsigned short bf16_bits(float f) {
    __hip_bfloat16 h = __float2bfloat16(f);  // RNE
    return *reinterpret_cast<unsigned short*>(&h);
}

// Kernel 1: 64x64 tile per block, 4 waves, each wave a 32x32 quadrant
// (2x2 frags of mfma_f32_16x16x32_bf16). BK=64. fp32->bf16 in staging.
// G symmetric so fragment row/col transposition is harmless.
__global__ __launch_bounds__(256) void k_gemm_mfma(const float* __restrict__ F,
                                                   float* __restrict__ G,
                                                   float* __restrict__ diag,
                                                   unsigned* __restrict__ counter,
                                                   int n, int d) {
    if (blockIdx.x == 0 && blockIdx.y == 0 && threadIdx.x == 0) *counter = 0u;

    __shared__ unsigned short Asm[64][72];  // 144 B row stride: 16B-aligned,
    __shared__ unsigned short Bsm[64][72];  // 2-way bank aliasing (free)

    const int t  = threadIdx.x;
    const int l  = t & 63;
    const int w  = t >> 6;
    const int wr = (w >> 1) << 5;   // wave quadrant row: 0 / 32
    const int wc = (w & 1) << 5;    // wave quadrant col: 0 / 32

    const int i0 = blockIdx.y << 6;
    const int j0 = blockIdx.x << 6;

    const int sr = t >> 2;          // staging row 0..63
    const int sc = (t & 3) << 4;    // staging col 0,16,32,48

    const int fr = l & 15;          // frag row/col within 16x16
    const int fk = (l >> 4) << 3;   // frag k base: 0,8,16,24

    f32x4 acc[2][2] = {};

    for (int k0 = 0; k0 < d; k0 += 64) {
        __syncthreads();  // previous iter's frag reads complete

        const float4* pa = (const float4*)&F[(size_t)(i0 + sr) * d + k0 + sc];
        const float4* pb = (const float4*)&F[(size_t)(j0 + sr) * d + k0 + sc];
        float fa[16], fb[16];
        *(float4*)(fa + 0)  = pa[0]; *(float4*)(fa + 4)  = pa[1];
        *(float4*)(fa + 8)  = pa[2]; *(float4*)(fa + 12) = pa[3];
        *(float4*)(fb + 0)  = pb[0]; *(float4*)(fb + 4)  = pb[1];
        *(float4*)(fb + 8)  = pb[2]; *(float4*)(fb + 12) = pb[3];

        ushort8 va0, va1, vb0, vb1;
        #pragma unroll
        for (int e = 0; e < 8; ++e) {
            va0[e] = bf16_bits(fa[e]);     va1[e] = bf16_bits(fa[e + 8]);
            vb0[e] = bf16_bits(fb[e]);     vb1[e] = bf16_bits(fb[e + 8]);
        }
        *(ushort8*)&Asm[sr][sc]     = va0;
        *(ushort8*)&Asm[sr][sc + 8] = va1;
        *(ushort8*)&Bsm[sr][sc]     = vb0;
        *(ushort8*)&Bsm[sr][sc + 8] = vb1;

        __syncthreads();

        #pragma unroll
        for (int ks = 0; ks < 2; ++ks) {
            short8 af0 = *(const short8*)&Asm[wr + fr     ][ks * 32 + fk];
            short8 af1 = *(const short8*)&Asm[wr + 16 + fr][ks * 32 + fk];
            short8 bf0 = *(const short8*)&Bsm[wc + fr     ][ks * 32 + fk];
            short8 bf1 = *(const short8*)&Bsm[wc + 16 + fr][ks * 32 + fk];
            acc[0][0] = __builtin_amdgcn_mfma_f32_16x16x32_bf16(af0, bf0, acc[0][0], 0, 0, 0);
            acc[0][1] = __builtin_amdgcn_mfma_f32_16x16x32_bf16(af0, bf1, acc[0][1], 0, 0, 0);
            acc[1][0] = __builtin_amdgcn_mfma_f32_16x16x32_bf16(af1, bf0, acc[1][0], 0, 0, 0);
            acc[1][1] = __builtin_amdgcn_mfma_f32_16x16x32_bf16(af1, bf1, acc[1][1], 0, 0, 0);
        }
    }

    const int orow = (l >> 4) << 2;
    #pragma unroll
    for (int mi = 0; mi < 2; ++mi) {
        #pragma unroll
        for (int ni = 0; ni < 2; ++ni) {
            #pragma unroll
            for (int r = 0; r < 4; ++r) {
                int gi = i0 + wr + mi * 16 + orow + r;
                int gj = j0 + wc + ni * 16 + fr;
                float v = acc[mi][ni][r];
                G[(size_t)gi * n + gj] = v;
                if (gi == gj) diag[gi] = v;
            }
        }
    }
}

// Kernel 2: one block (256 threads) per row i. Sort + suffix-sum method.
__global__ __launch_bounds__(256) void k_loss(const float* __restrict__ labels,
                                              const float* __restrict__ G,
                                              const float* __restrict__ diag,
                                              float* __restrict__ row_sums,
                                              unsigned* __restrict__ counter,
                                              float* __restrict__ out,
                                              int n) {
    const int i = blockIdx.x;
    const int t = threadIdx.x;
    __shared__ float2 lde[512];     // (.x = label_diff, .y = exp_logit)
    __shared__ float  suf[512];     // suffix sums of sorted e
    __shared__ float  lab_s[512];
    __shared__ float  dg_s[512];
    __shared__ float  red[4];
    __shared__ int    flag_s;

    for (int j = t; j < n; j += 256) {
        lab_s[j] = labels[j];
        dg_s[j]  = diag[j];
    }
    __syncthreads();

    const float li = lab_s[i];
    const float di = dg_s[i];
    const float* Grow = G + (size_t)i * n;

    // ---- build (ld, e) pairs; keep own k-values in registers ----
    float lgt[2], ldk[2];
    #pragma unroll
    for (int q = 0; q < 2; ++q) {
        int j = t + q * 256;
        float g  = Grow[j] * rsqrtf(di * dg_s[j]);
        float sq = fmaxf(2.f - 2.f * g, 0.f);
        float lg = 0.5f * sqrtf(sq);
        float e  = (j == i) ? 0.f : expf(lg);
        float ld = fabsf(li - lab_s[j]);
        lde[j] = make_float2(ld, e);
        lgt[q] = lg;
        ldk[q] = ld;   // identical bits to lde[j].x -> exact >= semantics
    }
    __syncthreads();

    // ---- bitonic sort by .x ascending (n = 512, 45 rounds) ----
    for (int k = 2; k <= n; k <<= 1) {
        for (int s = k >> 1; s > 0; s >>= 1) {
            #pragma unroll
            for (int q = 0; q < 2; ++q) {
                int x = t + q * 256;
                int y = x ^ s;
                if (y > x) {
                    float2 a = lde[x];
                    float2 b = lde[y];
                    bool up = ((x & k) == 0);
                    if (up ? (a.x > b.x) : (a.x < b.x)) {
                        lde[x] = b;
                        lde[y] = a;
                    }
                }
            }
            __syncthreads();
        }
    }

    // ---- inclusive suffix sum of e over sorted order (Hillis-Steele) ----
    suf[t]       = lde[t].y;
    suf[t + 256] = lde[t + 256].y;
    __syncthreads();
    for (int off = 1; off < n; off <<= 1) {
        float v0 = suf[t]       + ((t + off < n)       ? suf[t + off]       : 0.f);
        float v1 = suf[t + 256] + ((t + 256 + off < n) ? suf[t + 256 + off] : 0.f);
        __syncthreads();
        suf[t]       = v0;
        suf[t + 256] = v1;
        __syncthreads();
    }

    // ---- per-k: denom = suf[lower_bound(ld_k)] ----
    float acc = 0.f;
    #pragma unroll
    for (int q = 0; q < 2; ++q) {
        int kidx = t + q * 256;
        if (kidx == i) continue;
        float key = ldk[q];
        int lo = 0, hi = n;
        while (lo < hi) {                 // first idx with lde[idx].x >= key
            int mid = (lo + hi) >> 1;
            if (lde[mid].x < key) lo = mid + 1; else hi = mid;
        }
        acc += lgt[q] - logf(suf[lo]);    // key is in array -> lo < n
    }

    // ---- block reduce + last-block deterministic final reduction ----
    #pragma unroll
    for (int off = 32; off > 0; off >>= 1) acc += __shfl_down(acc, off);
    const int lane = t & 63, wid = t >> 6;
    if (lane == 0) red[wid] = acc;
    __syncthreads();
    if (t == 0) {
        float rs = red[0] + red[1] + red[2] + red[3];
        __hip_atomic_store(&row_sums[i], rs, __ATOMIC_RELEASE,
                           __HIP_MEMORY_SCOPE_AGENT);
        unsigned prev = __hip_atomic_fetch_add(counter, 1u, __ATOMIC_ACQ_REL,
                                               __HIP_MEMORY_SCOPE_AGENT);
        flag_s = (prev == (unsigned)(gridDim.x - 1));
    }
    __syncthreads();

    if (flag_s) {
        float s = 0.f;
        for (int r = t; r < n; r += 256)
            s += __hip_atomic_load(&row_sums[r], __ATOMIC_ACQUIRE,
                                   __HIP_MEMORY_SCOPE_AGENT);
        #pragma unroll
        for (int off = 32; off > 0; off >>= 1) s += __shfl_down(s, off);
        if (lane == 0) red[wid] = s;
        __syncthreads();
        if (t == 0) {
            float tot = red[0] + red[1] + red[2] + red[3];
            out[0] = -tot / ((float)n * ((float)n - 1.0f));
        }
    }
}

extern "C" void kernel_launch(void* const* d_in, const int* in_sizes, int n_in,
                              void* d_out, int out_size, void* d_ws, size_t ws_size,
                              hipStream_t stream) {
    const float* F      = (const float*)d_in[0];
    const float* labels = (const float*)d_in[1];
    int n = in_sizes[1];            // 512
    int d = in_sizes[0] / n;        // 512
    float* out = (float*)d_out;

    char* ws = (char*)d_ws;
    unsigned* counter = (unsigned*)ws;                  // 4 B
    float* row_sums   = (float*)(ws + 4096);            // n floats
    float* diag       = (float*)(ws + 8192);            // n floats
    float* G          = (float*)(ws + 16384);           // n*n fp32

    dim3 g(n / 64, n / 64);
    k_gemm_mfma<<<g, 256, 0, stream>>>(F, G, diag, counter, n, d);
    k_loss<<<n, 256, 0, stream>>>(labels, G, diag, row_sums, counter, out, n);
}